// Round 6
// baseline (4435.753 us; speedup 1.0000x reference)
//
#include <hip/hip_runtime.h>
#include <math.h>

#define NA      128
#define NBATCH  2048
#define NTHR    512     // R4 lesson: HW caps ~4 WORKGROUPS/CU regardless of size
                        // -> biggest blocks maximize waves/CU (28 vs 13).
#define NIT     300
#define NBIS    40      // full 40: prev-session R7: NBIS=24 -> absmax 8e-3
#define LRC     0.02f
#define EPSC    1e-8f

// ---- wave64 cross-lane reductions via DPP (VALU pipe, no LDS traffic) ----
// The DPP tree ORDER is part of the fp contract (absmax dice): never change it.
template <int CTRL>
__device__ __forceinline__ float dpp_sum_step(float x) {
  int s = __builtin_amdgcn_update_dpp(0, __float_as_int(x), CTRL, 0xF, 0xF, true);
  return x + __int_as_float(s);
}
__device__ __forceinline__ float wave_sum64(float x) {
  x = dpp_sum_step<0x111>(x);
  x = dpp_sum_step<0x112>(x);
  x = dpp_sum_step<0x114>(x);
  x = dpp_sum_step<0x118>(x);
  x = dpp_sum_step<0x142>(x);
  x = dpp_sum_step<0x143>(x);
  return x;  // total in lane 63
}
template <int CTRL>
__device__ __forceinline__ float dpp_mov_self(float x) {
  int s = __builtin_amdgcn_update_dpp(__float_as_int(x), __float_as_int(x), CTRL, 0xF, 0xF, false);
  return __int_as_float(s);
}
__device__ __forceinline__ float wave_min64(float x) {
  x = fminf(x, dpp_mov_self<0x111>(x));
  x = fminf(x, dpp_mov_self<0x112>(x));
  x = fminf(x, dpp_mov_self<0x114>(x));
  x = fminf(x, dpp_mov_self<0x118>(x));
  x = fminf(x, dpp_mov_self<0x142>(x));
  x = fminf(x, dpp_mov_self<0x143>(x));
  return x;  // min in lane 63
}
__device__ __forceinline__ float wave_max64(float x) {
  x = fmaxf(x, dpp_mov_self<0x111>(x));
  x = fmaxf(x, dpp_mov_self<0x112>(x));
  x = fmaxf(x, dpp_mov_self<0x114>(x));
  x = fmaxf(x, dpp_mov_self<0x118>(x));
  x = fmaxf(x, dpp_mov_self<0x142>(x));
  x = fmaxf(x, dpp_mov_self<0x143>(x));
  return x;  // max in lane 63
}
__device__ __forceinline__ float bcast63(float x) {
  return __int_as_float(__builtin_amdgcn_readlane(__float_as_int(x), 63));
}
__device__ __forceinline__ float clip1(float x) {
  return __builtin_amdgcn_fmed3f(x, -1.0f, 1.0f);  // c = MAX_WEIGHT = 1
}

// One block per batch element, 512 threads (8 waves). Thread (r = tid&127,
// q = tid>>7) owns quarter-row r, cols 32q..32q+31.
//
// R12/R13: HALF-LDS-A. Forensic: 40.2 GB/dispatch of A re-reads
// (2048 x 65.5KB x 300) served by L2/L3 at ~15 TB/s sustained; per-XCD
// working set 8.4MB thrashes the 4MB L2 -> L3-BW-bound matvec; at L3 rate
// the A-fetch alone ~= the whole measured iteration (10.9K vs 10.8K cy).
// Full-LDS-A died before (65KB -> 2 blocks/CU); registers die on the
// allocator (R2/R9 spills). Compromise: quarters q=0,1 (cols 0-63, 32KB,
// gm folded ONCE at stage = same rounding as per-iter t*gm) live in LDS
// with XOR granule swizzle slot = c4 ^ (r&7) (each 8-lane group covers all
// 32 banks -> b128 floor rate); waves 4-7 stream q=2,3 from cache.
// Traffic halves; remaining working set ~4.2MB/XCD ~fits L2; LDS 35.9KB
// keeps 4 blocks/CU. All fp values/orders identical -> absmax must stay
// exactly 2.288818e-3.
__global__ __launch_bounds__(NTHR)
void markowitz_kernel(
    const float* __restrict__ rets,
    const float* __restrict__ covmat,
    const float* __restrict__ gamma,
    const float* __restrict__ alpha,
    float* __restrict__ out)
{
  const int b    = blockIdx.x;
  const int tid  = threadIdx.x;
  const int r    = tid & (NA - 1);  // row 0..127
  const int q    = tid >> 7;        // quarter 0..3 (uniform within a wave)
  const int lane = tid & 63;
  const int wv   = tid >> 6;        // wave 0..7
  const int chain_wv = b & 7;

  __shared__ __align__(16) float As[8192];   // 32KB: A * gm, quarters 0-1, swizzled
  __shared__ __align__(16) float ws[NA];     // current weights
  __shared__ __align__(16) float vs[NA];     // pre-projection vector
  __shared__ __align__(16) float part[NTHR]; // quarter-row dot partials
  __shared__ float pp[4];                    // wAw, ww per wave 0/1

  const float gm = gamma[b];
  const float av = fabsf(alpha[b]);
  const float* Ab = covmat + (size_t)b * NA * NA;

  // ---- one-time: stage cols 0-63 of all rows into LDS, gm folded, swizzled ----
  // granule g = (row r, col-granule c4 in 0..15); dest slot = c4 ^ (r&7).
  // 2048 granules / 512 threads = 4 each; wave reads 1KB contiguous global.
#pragma unroll
  for (int i = 0; i < 4; ++i) {
    const int g  = tid + i * NTHR;      // 0..2047
    const int rr = g >> 4;              // row 0..127
    const int c4 = g & 15;              // granule 0..15 (cols 0..63)
    float4 t = *reinterpret_cast<const float4*>(Ab + (size_t)rr * NA + c4 * 4);
    float4 v = make_float4(t.x * gm, t.y * gm, t.z * gm, t.w * gm);
    const int slot = c4 ^ (rr & 7);
    *reinterpret_cast<float4*>(reinterpret_cast<char*>(As) + rr * 256 + slot * 16) = v;
  }

  float r_c = 0.0f;
  if (tid < NA) { r_c = rets[b * NA + tid]; ws[tid] = 1.0f / NA; }
  __syncthreads();

  // global-path pointer (quarters 2,3) for waves 4-7
  const float4* Aq = reinterpret_cast<const float4*>(Ab + (size_t)r * NA + q * 32);
  // LDS-path swizzled base for waves 0-3: byte addr_k = base2 ^ (16k)
  const int base2 = r * 256 + q * 128 + (r & 7) * 16;

#pragma unroll 1
  for (int it = 0; it < NIT; ++it) {
    // ---- 1. quarter-row dot; w via wave-uniform LDS broadcast ----
    const float4* w4 = reinterpret_cast<const float4*>(ws) + q * 8;
    float4 acc = make_float4(0.f, 0.f, 0.f, 0.f);
    if (q < 2) {
      // LDS path: gm already folded at stage time (identical rounding)
#pragma unroll
      for (int k = 0; k < 8; ++k) {
        float4 ak = *reinterpret_cast<const float4*>(
            reinterpret_cast<const char*>(As) + (base2 ^ (16 * k)));
        float4 wk = w4[k];
        acc.x = fmaf(ak.x, wk.x, acc.x);
        acc.y = fmaf(ak.y, wk.y, acc.y);
        acc.z = fmaf(ak.z, wk.z, acc.z);
        acc.w = fmaf(ak.w, wk.w, acc.w);
      }
    } else {
      // global path: stream from L1/L2, fold gm per element (as baseline)
#pragma unroll
      for (int k = 0; k < 8; ++k) {
        float4 t  = Aq[k];
        float4 wk = w4[k];
        acc.x = fmaf(t.x * gm, wk.x, acc.x);
        acc.y = fmaf(t.y * gm, wk.y, acc.y);
        acc.z = fmaf(t.z * gm, wk.z, acc.z);
        acc.w = fmaf(t.w * gm, wk.w, acc.w);
      }
    }
    part[tid] = (acc.x + acc.y) + (acc.z + acc.w);
    __syncthreads();

    // ---- 2. combine quarters; wAw / ww reductions (waves 0,1) ----
    float Aw = 0.f, w_c = 0.f;
    if (tid < NA) {
      Aw  = (part[tid] + part[tid + NA]) + (part[tid + 2 * NA] + part[tid + 3 * NA]);
      w_c = ws[tid];
      float p1 = wave_sum64(w_c * Aw);
      float p2 = wave_sum64(w_c * w_c);
      if (lane == 63) { pp[wv * 2 + 0] = p1; pp[wv * 2 + 1] = p2; }
    }
    __syncthreads();

    // ---- 3. gradient step -> v (waves 0,1) ----
    if (tid < NA) {
      const float risk = sqrtf(pp[0] + pp[2] + EPSC);
      const float nrm  = sqrtf(pp[1] + pp[3] + EPSC);
      const float g    = r_c - Aw / risk - av * (w_c / nrm);
      vs[tid] = w_c + LRC * g;
    }
    __syncthreads();

    // ---- 4. bisection + projection on the chain wave only (serial, NBIS=40) ----
    if (wv == chain_wv) {
      float v0 = vs[lane];
      float v1 = vs[lane + 64];
      float mn = bcast63(wave_min64(fminf(v0, v1)));
      float mx = bcast63(wave_max64(fmaxf(v0, v1)));
      float lo = mn - 2.0f;   // min(v) - c - 1
      float hi = mx + 1.0f;   // max(v) + c
#pragma unroll 1
      for (int rr2 = 0; rr2 < NBIS; ++rr2) {
        const float mid = 0.5f * (lo + hi);
        float s = wave_sum64(clip1(v0 - mid) + clip1(v1 - mid));
        const float st = bcast63(s);
        const bool big = st > 1.0f;
        lo = big ? mid : lo;
        hi = big ? hi : mid;
      }
      const float tau = 0.5f * (lo + hi);
      ws[lane]      = clip1(v0 - tau);
      ws[lane + 64] = clip1(v1 - tau);
    }
    __syncthreads();
  }

  if (tid < NA) out[b * NA + tid] = ws[tid];
}

extern "C" void kernel_launch(void* const* d_in, const int* in_sizes, int n_in,
                              void* d_out, int out_size, void* d_ws, size_t ws_size,
                              hipStream_t stream) {
  const float* rets   = (const float*)d_in[0];
  const float* covmat = (const float*)d_in[1];
  const float* gamma  = (const float*)d_in[2];
  const float* alpha  = (const float*)d_in[3];
  float* out = (float*)d_out;

  hipLaunchKernelGGL(markowitz_kernel, dim3(NBATCH), dim3(NTHR), 0, stream,
                     rets, covmat, gamma, alpha, out);
}

// Round 7
// 2749.338 us; speedup vs baseline: 1.6134x; 1.6134x over previous
//
#include <hip/hip_runtime.h>
#include <math.h>

#define NA      128
#define NBATCH  2048
#define NTHR    512
#define NELB    2       // batch elements per block (waves 0-3 -> e0, waves 4-7 -> e1)
#define NIT     300
#define NBIS    40      // full 40: prev-session: NBIS=24 -> absmax 8e-3 (4e4x tau-noise amplification)
#define LRC     0.02f
#define EPSC    1e-8f

// ---- wave64 cross-lane reductions via DPP (VALU pipe, no LDS traffic) ----
// The DPP tree ORDER is part of the fp contract (absmax dice): never change it.
template <int CTRL>
__device__ __forceinline__ float dpp_sum_step(float x) {
  int s = __builtin_amdgcn_update_dpp(0, __float_as_int(x), CTRL, 0xF, 0xF, true);
  return x + __int_as_float(s);
}
__device__ __forceinline__ float wave_sum64(float x) {
  x = dpp_sum_step<0x111>(x);
  x = dpp_sum_step<0x112>(x);
  x = dpp_sum_step<0x114>(x);
  x = dpp_sum_step<0x118>(x);
  x = dpp_sum_step<0x142>(x);
  x = dpp_sum_step<0x143>(x);
  return x;  // total in lane 63
}
template <int CTRL>
__device__ __forceinline__ float dpp_mov_self(float x) {
  int s = __builtin_amdgcn_update_dpp(__float_as_int(x), __float_as_int(x), CTRL, 0xF, 0xF, false);
  return __int_as_float(s);
}
__device__ __forceinline__ float wave_min64(float x) {
  x = fminf(x, dpp_mov_self<0x111>(x));
  x = fminf(x, dpp_mov_self<0x112>(x));
  x = fminf(x, dpp_mov_self<0x114>(x));
  x = fminf(x, dpp_mov_self<0x118>(x));
  x = fminf(x, dpp_mov_self<0x142>(x));
  x = fminf(x, dpp_mov_self<0x143>(x));
  return x;  // min in lane 63
}
__device__ __forceinline__ float wave_max64(float x) {
  x = fmaxf(x, dpp_mov_self<0x111>(x));
  x = fmaxf(x, dpp_mov_self<0x112>(x));
  x = fmaxf(x, dpp_mov_self<0x114>(x));
  x = fmaxf(x, dpp_mov_self<0x118>(x));
  x = fmaxf(x, dpp_mov_self<0x142>(x));
  x = fmaxf(x, dpp_mov_self<0x143>(x));
  return x;  // max in lane 63
}
__device__ __forceinline__ float bcast63(float x) {
  return __int_as_float(__builtin_amdgcn_readlane(__float_as_int(x), 63));
}
__device__ __forceinline__ float clip1(float x) {
  return __builtin_amdgcn_fmed3f(x, -1.0f, 1.0f);  // c = MAX_WEIGHT = 1
}

// R14 (this round): TWO ELEMENTS PER WORKGROUP.
//  Forensic chain: HW caps ~4 WORKGROUPS/CU regardless of block size (R4:
//  256-thr -> occ 42% = same ~3.4 blocks/CU as 512-thr's 3.5). At 2048
//  blocks that means TWO sequential dispatch rounds, and only ~4 serial
//  bisect chains per CU to hide each other -> VALUBusy pinned ~50%.
//  LDS-A (R6) and reg-A (R2/R9) residency fixes both lose more than they
//  gain (bank conflicts / occupancy / spills). So: pack 2 batch elements
//  per 512-thr block. Waves 0-3 run element 2b, waves 4-7 run 2b+1, each
//  as R4's 256-thread scheme (HW-verified bit-exact: R4 absmax matched to
//  the last digit; it was only slow from occupancy). 1024 blocks -> exactly
//  4/CU -> ONE dispatch round; 8 resident elements/CU; chains per half on
//  different SIMDs. absmax must stay exactly 2.288818e-3.
__global__ __launch_bounds__(NTHR)
void markowitz_kernel(
    const float* __restrict__ rets,
    const float* __restrict__ covmat,
    const float* __restrict__ gamma,
    const float* __restrict__ alpha,
    float* __restrict__ out)
{
  const int b    = blockIdx.x;      // 0..1023
  const int tid  = threadIdx.x;     // 0..511
  const int h    = tid >> 8;        // half 0/1 (wave-uniform)
  const int st   = tid & 255;       // sub-tid within element
  const int e    = b * NELB + h;    // batch element
  const int r    = st & (NA - 1);   // row 0..127
  const int q0   = st >> 7;         // first quarter 0/1 (handles q0 and q0+2)
  const int lane = tid & 63;
  const int wvl  = st >> 6;         // local wave 0..3 within the half
  // chain wave per half: different local index per half -> different SIMD;
  // mixed with b so co-resident blocks also spread.
  const int c0 = b & 3;
  const int chain_loc = h ? ((c0 + 2) & 3) : c0;

  __shared__ __align__(16) float ws[NELB][NA];    // current weights
  __shared__ __align__(16) float vs[NELB][NA];    // pre-projection vector
  __shared__ __align__(16) float part[NELB][512]; // quarter partials, slot r+128q
  __shared__ float pp[NELB][4];                   // wAw, ww per local wave 0/1

  const float gm = gamma[e];
  const float av = fabsf(alpha[e]);
  const float* Ab   = covmat + (size_t)e * NA * NA;
  const float* Arow = Ab + (size_t)r * NA + q0 * 32;
  const float4* Aq0 = reinterpret_cast<const float4*>(Arow);       // quarter q0
  const float4* Aq1 = reinterpret_cast<const float4*>(Arow + 64);  // quarter q0+2

  float r_c = 0.0f;
  if (st < NA) { r_c = rets[e * NA + st]; ws[h][st] = 1.0f / NA; }
  __syncthreads();

#pragma unroll 1
  for (int it = 0; it < NIT; ++it) {
    // ---- 1. two quarter-row dots per thread (A streamed from cache,
    //         gm folded per element exactly as before; w via wave-uniform
    //         LDS broadcast) ----
    const float4* w40 = reinterpret_cast<const float4*>(ws[h]) + q0 * 8;
    const float4* w41 = w40 + 16;  // quarter q0+2
    float4 acc0 = make_float4(0.f, 0.f, 0.f, 0.f);
    float4 acc1 = make_float4(0.f, 0.f, 0.f, 0.f);
#pragma unroll
    for (int k = 0; k < 8; ++k) {
      float4 t0  = Aq0[k];
      float4 wk0 = w40[k];
      acc0.x = fmaf(t0.x * gm, wk0.x, acc0.x);
      acc0.y = fmaf(t0.y * gm, wk0.y, acc0.y);
      acc0.z = fmaf(t0.z * gm, wk0.z, acc0.z);
      acc0.w = fmaf(t0.w * gm, wk0.w, acc0.w);
      float4 t1  = Aq1[k];
      float4 wk1 = w41[k];
      acc1.x = fmaf(t1.x * gm, wk1.x, acc1.x);
      acc1.y = fmaf(t1.y * gm, wk1.y, acc1.y);
      acc1.z = fmaf(t1.z * gm, wk1.z, acc1.z);
      acc1.w = fmaf(t1.w * gm, wk1.w, acc1.w);
    }
    part[h][st]       = (acc0.x + acc0.y) + (acc0.z + acc0.w);  // slot r+128*q0
    part[h][st + 256] = (acc1.x + acc1.y) + (acc1.z + acc1.w);  // slot r+128*(q0+2)
    __syncthreads();

    // ---- 2. combine quarters; wAw / ww reductions (local waves 0,1) ----
    float Aw = 0.f, w_c = 0.f;
    if (st < NA) {
      Aw  = (part[h][st] + part[h][st + NA]) +
            (part[h][st + 2 * NA] + part[h][st + 3 * NA]);
      w_c = ws[h][st];
      float p1 = wave_sum64(w_c * Aw);
      float p2 = wave_sum64(w_c * w_c);
      if (lane == 63) { pp[h][wvl * 2 + 0] = p1; pp[h][wvl * 2 + 1] = p2; }
    }
    __syncthreads();

    // ---- 3. gradient step -> v (local waves 0,1) ----
    if (st < NA) {
      const float risk = sqrtf(pp[h][0] + pp[h][2] + EPSC);
      const float nrm  = sqrtf(pp[h][1] + pp[h][3] + EPSC);
      const float g    = r_c - Aw / risk - av * (w_c / nrm);
      vs[h][st] = w_c + LRC * g;
    }
    __syncthreads();

    // ---- 4. bisection + projection on this half's chain wave (serial, NBIS=40) ----
    if (wvl == chain_loc) {
      float v0 = vs[h][lane];
      float v1 = vs[h][lane + 64];
      float mn = bcast63(wave_min64(fminf(v0, v1)));
      float mx = bcast63(wave_max64(fmaxf(v0, v1)));
      float lo = mn - 2.0f;   // min(v) - c - 1
      float hi = mx + 1.0f;   // max(v) + c
#pragma unroll 1
      for (int rr = 0; rr < NBIS; ++rr) {
        const float mid = 0.5f * (lo + hi);
        float s = wave_sum64(clip1(v0 - mid) + clip1(v1 - mid));
        const float st2 = bcast63(s);
        const bool big = st2 > 1.0f;
        lo = big ? mid : lo;
        hi = big ? hi : mid;
      }
      const float tau = 0.5f * (lo + hi);
      ws[h][lane]      = clip1(v0 - tau);
      ws[h][lane + 64] = clip1(v1 - tau);
    }
    __syncthreads();
  }

  if (st < NA) out[e * NA + st] = ws[h][st];
}

extern "C" void kernel_launch(void* const* d_in, const int* in_sizes, int n_in,
                              void* d_out, int out_size, void* d_ws, size_t ws_size,
                              hipStream_t stream) {
  const float* rets   = (const float*)d_in[0];
  const float* covmat = (const float*)d_in[1];
  const float* gamma  = (const float*)d_in[2];
  const float* alpha  = (const float*)d_in[3];
  float* out = (float*)d_out;

  hipLaunchKernelGGL(markowitz_kernel, dim3(NBATCH / NELB), dim3(NTHR), 0, stream,
                     rets, covmat, gamma, alpha, out);
}